// Round 9
// baseline (1001.033 us; speedup 1.0000x reference)
//
#include <hip/hip_runtime.h>

#define TPB 256

typedef __attribute__((ext_vector_type(4))) float f32x4;
typedef __attribute__((ext_vector_type(8))) short s16x8;

__device__ __forceinline__ ushort f2bf(float f) {
  unsigned x = __float_as_uint(f);
  return (ushort)((x + 0x7fffu + ((x >> 16) & 1u)) >> 16);
}
__device__ __forceinline__ float b2f(ushort u) {
  return __uint_as_float(((unsigned)u) << 16);
}
__device__ __forceinline__ void gload_lds16(const ushort* g, ushort* l) {
  __builtin_amdgcn_global_load_lds(
      (const __attribute__((address_space(1))) void*)g,
      (__attribute__((address_space(3))) void*)l, 16, 0, 0);
}

__device__ __forceinline__ float blk_sum(float v, float* red, int tid) {
#pragma unroll
  for (int o = 32; o; o >>= 1) v += __shfl_xor(v, o);
  if ((tid & 63) == 0) red[tid >> 6] = v;
  __syncthreads();
  float r = red[0] + red[1] + red[2] + red[3];
  __syncthreads();
  return r;
}

// ---------------------------------------------------------------------------
// GEMM v2 (conv_fused2 skeleton): C[M,N] = A[M,K] @ Bt[N,K]^T (+bias,+res).
// BM=256 x BN=128, BK=64, 8 waves (4Mx2N, wave-tile 64x64), 512 threads.
// Triple-buffered LDS (144KB dynamic), counted vmcnt(6), slot-XOR swizzle
// (verified 0 bank conflicts), setprio around MFMA clusters.
// ---------------------------------------------------------------------------
template<bool C_BF16, bool HAS_BIAS, bool HAS_RES>
__global__ __launch_bounds__(512, 2)
void gemm_bt2(const ushort* __restrict__ A, int lda,
              const ushort* __restrict__ B, int ldb,
              void* __restrict__ Cp, int ldc,
              const float* __restrict__ bias, const float* __restrict__ Res,
              int K)
{
  extern __shared__ ushort smem[];      // [3][256*64] A + [3][128*64] B
  ushort* lA = smem;
  ushort* lB = smem + 49152;
  const int tid = threadIdx.x;
  const int rowBase = blockIdx.x * 256;
  const int colBase = blockIdx.y * 128;
  const int w = tid >> 6, lane = tid & 63;
  const int wrm = w >> 1, wcn = w & 1;
  const int lr = lane & 15, kg = lane >> 4;
  const int nsteps = K >> 6;            // 16 for K=1024

  f32x4 acc[4][4] = {};

  auto stage = [&](int t, int buf) {
    const int k0 = t * 64;
    ushort* dA = lA + buf * 16384;
    ushort* dB = lB + buf * 8192;
#pragma unroll
    for (int i = 0; i < 4; ++i) {       // A: 256 rows x 8 slots
      int li = i * 512 + tid;
      int r = li >> 3, sl = li & 7;
      int gsl = sl ^ (r & 7);
      gload_lds16(A + (long)(rowBase + r) * lda + k0 + gsl * 8, dA + li * 8);
    }
#pragma unroll
    for (int i = 0; i < 2; ++i) {       // B: 128 rows x 8 slots
      int li = i * 512 + tid;
      int r = li >> 3, sl = li & 7;
      int gsl = sl ^ (r & 7);
      gload_lds16(B + (long)(colBase + r) * ldb + k0 + gsl * 8, dB + li * 8);
    }
  };

  stage(0, 0);
  stage(1, 1);
  __builtin_amdgcn_sched_barrier(0);
  asm volatile("s_waitcnt vmcnt(6)" ::: "memory");
  __builtin_amdgcn_sched_barrier(0);
  __syncthreads();

#pragma unroll 3
  for (int t = 0; t < nsteps; ++t) {
    const int cur = t % 3;
    if (t + 2 < nsteps) stage(t + 2, (t + 2) % 3);

    const ushort* bA = lA + cur * 16384;
    const ushort* bB = lB + cur * 8192;
#pragma unroll
    for (int ks = 0; ks < 2; ++ks) {
      s16x8 af[4], bfr[4];
#pragma unroll
      for (int mf = 0; mf < 4; ++mf) {
        int r = wrm * 64 + mf * 16 + lr;
        int sl = (ks * 4 + kg) ^ (r & 7);
        af[mf] = *(const s16x8*)&bA[r * 64 + sl * 8];
      }
#pragma unroll
      for (int nf = 0; nf < 4; ++nf) {
        int r = wcn * 64 + nf * 16 + lr;
        int sl = (ks * 4 + kg) ^ (r & 7);
        bfr[nf] = *(const s16x8*)&bB[r * 64 + sl * 8];
      }
      __builtin_amdgcn_s_setprio(1);
#pragma unroll
      for (int mf = 0; mf < 4; ++mf)
#pragma unroll
        for (int nf = 0; nf < 4; ++nf)
          acc[mf][nf] = __builtin_amdgcn_mfma_f32_16x16x32_bf16(af[mf], bfr[nf], acc[mf][nf], 0, 0, 0);
      __builtin_amdgcn_s_setprio(0);
    }

    __builtin_amdgcn_sched_barrier(0);
    if (t + 2 < nsteps)      asm volatile("s_waitcnt vmcnt(6)" ::: "memory");
    else if (t + 1 < nsteps) asm volatile("s_waitcnt vmcnt(0)" ::: "memory");
    __builtin_amdgcn_sched_barrier(0);
    __syncthreads();
  }

  const int crow0 = rowBase + wrm * 64 + kg * 4;
#pragma unroll
  for (int mf = 0; mf < 4; ++mf)
#pragma unroll
    for (int nf = 0; nf < 4; ++nf) {
      const int col = colBase + wcn * 64 + nf * 16 + lr;
      const float bv = HAS_BIAS ? bias[col] : 0.f;
#pragma unroll
      for (int j = 0; j < 4; ++j) {
        const long off = (long)(crow0 + mf * 16 + j) * ldc + col;
        float v = acc[mf][nf][j] + bv;
        if (HAS_RES) v += Res[off];
        if (C_BF16) ((ushort*)Cp)[off] = f2bf(v);
        else        ((float*)Cp)[off] = v;
      }
    }
}

// ---------------------------------------------------------------------------
// Fused conv FFN v2 + T5: x += mean_br relu(bn_br(conv_br(A))).
// BM=256 x BN=128, BK=64, 8 waves, grid 256 = 1/CU, triple-buffered LDS,
// counted vmcnt(6), slot-XOR swizzle (0 bank conflicts), setprio (R8: +8%).
// ---------------------------------------------------------------------------
__global__ __launch_bounds__(512, 2)
void conv_fused2(const ushort* __restrict__ A, const ushort* __restrict__ W9,
                 float* __restrict__ x, const float* __restrict__ sc,
                 const float* __restrict__ sh, const ushort* __restrict__ zp)
{
  extern __shared__ ushort smem[];      // [3][256*64] A + [3][128*64] B
  ushort* lA = smem;
  ushort* lB = smem + 49152;
  const int tid = threadIdx.x;
  const int rowBase = blockIdx.x * 256;
  const int colBase = blockIdx.y * 128;
  const int w = tid >> 6, lane = tid & 63;
  const int wrm = w >> 1, wcn = w & 1;
  const int lr = lane & 15, kg = lane >> 4;

  f32x4 acc[4][4] = {};
  f32x4 res[4][4] = {};

  auto stage = [&](int t, int buf) {
    const int s = t >> 4;                                   // segment 0..8
    const int k0 = (t & 15) * 64;
    const int shift = (s == 0) ? 0 : ((s <= 3) ? s - 2 : s - 6);
    const ushort* Wseg = W9 + (long)s * 1048576 + k0;
    const ushort* Ak = A + k0;
    ushort* dA = lA + buf * 16384;
    ushort* dB = lB + buf * 8192;
#pragma unroll
    for (int i = 0; i < 4; ++i) {
      int li = i * 512 + tid;
      int r = li >> 3, sl = li & 7;
      int gsl = sl ^ (r & 7);
      int gr = rowBase + r;
      int sr = (gr & 1023) + shift;
      const ushort* src = ((unsigned)sr < 1024u)
          ? (Ak + (long)((gr & ~1023) + sr) * 1024 + gsl * 8) : zp;
      gload_lds16(src, dA + li * 8);
    }
#pragma unroll
    for (int i = 0; i < 2; ++i) {
      int li = i * 512 + tid;
      int r = li >> 3, sl = li & 7;
      int gsl = sl ^ (r & 7);
      gload_lds16(Wseg + (long)(colBase + r) * 1024 + gsl * 8, dB + li * 8);
    }
  };

  stage(0, 0);
  stage(1, 1);
  __builtin_amdgcn_sched_barrier(0);
  asm volatile("s_waitcnt vmcnt(6)" ::: "memory");
  __builtin_amdgcn_sched_barrier(0);
  __syncthreads();

#pragma unroll 3
  for (int t = 0; t < 144; ++t) {
    const int cur = t % 3;
    if (t + 2 < 144) stage(t + 2, (t + 2) % 3);

    const ushort* bA = lA + cur * 16384;
    const ushort* bB = lB + cur * 8192;
#pragma unroll
    for (int ks = 0; ks < 2; ++ks) {
      s16x8 af[4], bfr[4];
#pragma unroll
      for (int mf = 0; mf < 4; ++mf) {
        int r = wrm * 64 + mf * 16 + lr;
        int sl = (ks * 4 + kg) ^ (r & 7);
        af[mf] = *(const s16x8*)&bA[r * 64 + sl * 8];
      }
#pragma unroll
      for (int nf = 0; nf < 4; ++nf) {
        int r = wcn * 64 + nf * 16 + lr;
        int sl = (ks * 4 + kg) ^ (r & 7);
        bfr[nf] = *(const s16x8*)&bB[r * 64 + sl * 8];
      }
      __builtin_amdgcn_s_setprio(1);
#pragma unroll
      for (int mf = 0; mf < 4; ++mf)
#pragma unroll
        for (int nf = 0; nf < 4; ++nf)
          acc[mf][nf] = __builtin_amdgcn_mfma_f32_16x16x32_bf16(af[mf], bfr[nf], acc[mf][nf], 0, 0, 0);
      __builtin_amdgcn_s_setprio(0);
    }

    if (t == 15 || t == 63 || t == 143) {     // branch boundary fold
      const int br = (t == 15) ? 0 : (t == 63 ? 1 : 2);
#pragma unroll
      for (int nf = 0; nf < 4; ++nf) {
        const int col = colBase + wcn * 64 + nf * 16 + lr;
        const float scv = sc[br * 1024 + col];
        const float shv = sh[br * 1024 + col];
#pragma unroll
        for (int mf = 0; mf < 4; ++mf)
#pragma unroll
          for (int j = 0; j < 4; ++j) {
            res[mf][nf][j] += fmaxf(acc[mf][nf][j] * scv + shv, 0.f);
            acc[mf][nf][j] = 0.f;
          }
      }
    }

    __builtin_amdgcn_sched_barrier(0);
    if (t + 2 < 144)      asm volatile("s_waitcnt vmcnt(6)" ::: "memory");
    else if (t + 1 < 144) asm volatile("s_waitcnt vmcnt(0)" ::: "memory");
    __builtin_amdgcn_sched_barrier(0);
    __syncthreads();
  }

  const int crow0 = rowBase + wrm * 64 + kg * 4;
#pragma unroll
  for (int mf = 0; mf < 4; ++mf)
#pragma unroll
    for (int nf = 0; nf < 4; ++nf) {
      const int col = colBase + wcn * 64 + nf * 16 + lr;
#pragma unroll
      for (int j = 0; j < 4; ++j) {
        const long off = (long)(crow0 + mf * 16 + j) * 1024 + col;
        x[off] += res[mf][nf][j] * (1.f / 3.f);
      }
    }
}

// ---------------------------------------------------------------------------
// Flash attention v2: grid (8 q-tiles, 128 bh), 4 waves x 32 q-rows, KV=64.
// KV double-buffered, 1 barrier/tile, setprio around MFMA clusters.
// ---------------------------------------------------------------------------
__global__ __launch_bounds__(TPB)
void flash_attn(const ushort* __restrict__ qkv, const ushort* __restrict__ vt,
                ushort* __restrict__ obuf)
{
  __shared__ ushort lK[2][64 * 64];   // [pb][kv][d]
  __shared__ ushort lVt[2][64 * 64];  // [pb][d][kv]
  __shared__ ushort lP[4 * 32 * 64];  // per-wave [q][kv]
  const int tid = threadIdx.x;
  const int w = tid >> 6, lane = tid & 63;
  const int g = lane >> 4, c = lane & 15;
  const int bh = blockIdx.y, b = bh >> 4, h = bh & 15;
  const int qw = blockIdx.x * 128 + w * 32;
  const float c8 = 0.18033688f;       // log2(e)/8  -> softmax(s/8)

  auto stage = [&](int t, int pb) {
    const int kv0 = t * 64;
#pragma unroll
    for (int i = 0; i < 2; ++i) {     // K tile: [kv][64]
      int idx = i * TPB + tid;
      int r = idx >> 3, dc = (idx & 7) * 8;
      gload_lds16(qkv + (long)((b << 10) + kv0 + r) * 3072 + 1024 + (h << 6) + dc,
                  &lK[pb][idx * 8]);
    }
#pragma unroll
    for (int i = 0; i < 2; ++i) {     // V^T tile: [d][64]
      int idx = i * TPB + tid;
      int r = idx >> 3, dc = (idx & 7) * 8;
      gload_lds16(vt + (long)((bh << 6) + r) * 1024 + kv0 + dc, &lVt[pb][idx * 8]);
    }
  };

  s16x8 qfr[2][2];
#pragma unroll
  for (int qf = 0; qf < 2; ++qf)
#pragma unroll
    for (int ds = 0; ds < 2; ++ds)
      qfr[qf][ds] = *(const s16x8*)(qkv
          + (long)((b << 10) + qw + qf * 16 + c) * 3072 + (h << 6) + ds * 32 + g * 8);

  f32x4 acc_o[2][4] = {};
  float m[2][4], l[2][4];
#pragma unroll
  for (int qf = 0; qf < 2; ++qf)
#pragma unroll
    for (int j = 0; j < 4; ++j) { m[qf][j] = -3.0e38f; l[qf][j] = 0.f; }

  ushort* lPw = &lP[w * 2048];

  stage(0, 0);
  __builtin_amdgcn_sched_barrier(0);
  asm volatile("s_waitcnt vmcnt(0)" ::: "memory");
  __builtin_amdgcn_sched_barrier(0);
  __syncthreads();

  for (int t = 0; t < 16; ++t) {
    const int pb = t & 1;
    if (t + 1 < 16) stage(t + 1, pb ^ 1);

    // S = Q @ K^T : C[row=q, col=kv]
    f32x4 s[2][4] = {};
#pragma unroll
    for (int ds = 0; ds < 2; ++ds) {
      s16x8 bk[4];
#pragma unroll
      for (int kf = 0; kf < 4; ++kf)
        bk[kf] = *(const s16x8*)&lK[pb][(kf * 16 + c) * 64 + ds * 32 + g * 8];
      __builtin_amdgcn_s_setprio(1);
#pragma unroll
      for (int qf = 0; qf < 2; ++qf)
#pragma unroll
        for (int kf = 0; kf < 4; ++kf)
          s[qf][kf] = __builtin_amdgcn_mfma_f32_16x16x32_bf16(qfr[qf][ds], bk[kf], s[qf][kf], 0, 0, 0);
      __builtin_amdgcn_s_setprio(0);
    }

    // online softmax; row q = qf*16 + g*4 + j spans the 16 c-lanes
#pragma unroll
    for (int qf = 0; qf < 2; ++qf)
#pragma unroll
      for (int j = 0; j < 4; ++j) {
        float tm = fmaxf(fmaxf(s[qf][0][j], s[qf][1][j]), fmaxf(s[qf][2][j], s[qf][3][j]));
        tm = fmaxf(tm, __shfl_xor(tm, 1));
        tm = fmaxf(tm, __shfl_xor(tm, 2));
        tm = fmaxf(tm, __shfl_xor(tm, 4));
        tm = fmaxf(tm, __shfl_xor(tm, 8));
        float mn = fmaxf(m[qf][j], tm);
        float scale = exp2f((m[qf][j] - mn) * c8);
        m[qf][j] = mn;
        l[qf][j] *= scale;
#pragma unroll
        for (int df = 0; df < 4; ++df) acc_o[qf][df][j] *= scale;
        float ps = 0.f;
#pragma unroll
        for (int kf = 0; kf < 4; ++kf) {
          float pv = exp2f((s[qf][kf][j] - mn) * c8);
          ps += pv;
          lPw[(qf * 16 + g * 4 + j) * 64 + kf * 16 + c] = f2bf(pv);
        }
        l[qf][j] += ps;   // lane-partial over kv ≡ c (mod 16); reduced at end
      }

    // O += P @ V
#pragma unroll
    for (int kvb = 0; kvb < 2; ++kvb) {
      s16x8 pA[2], vB[4];
#pragma unroll
      for (int qf = 0; qf < 2; ++qf)
        pA[qf] = *(const s16x8*)&lPw[(qf * 16 + c) * 64 + kvb * 32 + g * 8];
#pragma unroll
      for (int df = 0; df < 4; ++df)
        vB[df] = *(const s16x8*)&lVt[pb][(df * 16 + c) * 64 + kvb * 32 + g * 8];
      __builtin_amdgcn_s_setprio(1);
#pragma unroll
      for (int qf = 0; qf < 2; ++qf)
#pragma unroll
        for (int df = 0; df < 4; ++df)
          acc_o[qf][df] = __builtin_amdgcn_mfma_f32_16x16x32_bf16(pA[qf], vB[df], acc_o[qf][df], 0, 0, 0);
      __builtin_amdgcn_s_setprio(0);
    }

    __builtin_amdgcn_sched_barrier(0);
    asm volatile("s_waitcnt vmcnt(0)" ::: "memory");
    __builtin_amdgcn_sched_barrier(0);
    __syncthreads();
  }

#pragma unroll
  for (int qf = 0; qf < 2; ++qf)
#pragma unroll
    for (int j = 0; j < 4; ++j) {
      float lv = l[qf][j];
      lv += __shfl_xor(lv, 1);
      lv += __shfl_xor(lv, 2);
      lv += __shfl_xor(lv, 4);
      lv += __shfl_xor(lv, 8);
      float inv = 1.f / lv;
#pragma unroll
      for (int df = 0; df < 4; ++df)
        obuf[(long)((b << 10) + qw + qf * 16 + g * 4 + j) * 1024 + (h << 6) + df * 16 + c]
            = f2bf(acc_o[qf][df][j] * inv);
    }
}

// LayerNorm (torch variant: unbiased std, eps added to std). One block per row.
template<bool OBF>
__global__ __launch_bounds__(TPB)
void ln_rows(const float* __restrict__ X, const float* __restrict__ ga,
             const float* __restrict__ gb, void* __restrict__ out)
{
  __shared__ float red[4];
  const int tid = threadIdx.x;
  const long base = (long)blockIdx.x * 1024;
  f32x4 v = *(const f32x4*)&X[base + tid * 4];
  float mean = blk_sum(v[0] + v[1] + v[2] + v[3], red, tid) * (1.f / 1024.f);
  f32x4 d = v - mean;
  float qs = blk_sum(d[0]*d[0] + d[1]*d[1] + d[2]*d[2] + d[3]*d[3], red, tid);
  float inv = 1.f / (sqrtf(qs * (1.f / 1023.f)) + 1e-6f);
  f32x4 a4 = *(const f32x4*)&ga[tid * 4];
  f32x4 b4 = *(const f32x4*)&gb[tid * 4];
  f32x4 r = a4 * (d * inv) + b4;
  if (OBF) {
    ushort4 o4 = { f2bf(r[0]), f2bf(r[1]), f2bf(r[2]), f2bf(r[3]) };
    *(ushort4*)((ushort*)out + base + tid * 4) = o4;
  } else {
    *(f32x4*)((float*)out + base + tid * 4) = r;
  }
}

// vt[b*16+h][d=64][kv=1024] = qkv[(b*1024+kv)*3072 + 2048 + h*64 + d]
__global__ __launch_bounds__(TPB)
void vt_build(const ushort* __restrict__ qkv, ushort* __restrict__ vt)
{
  __shared__ ushort t[64][72];
  const int tid = threadIdx.x;
  const int bh = blockIdx.y, b = bh >> 4, h = bh & 15;
  const int kv0 = blockIdx.x * 64;
#pragma unroll
  for (int it = 0; it < 2; ++it) {
    int idx = (it * TPB + tid) * 8;
    int r = idx >> 6, cc = idx & 63;
    s16x8 v = *(const s16x8*)(qkv + ((long)((b << 10) + kv0 + r)) * 3072 + 2048 + (h << 6) + cc);
#pragma unroll
    for (int j = 0; j < 8; ++j) t[r][cc + j] = (ushort)v[j];
  }
  __syncthreads();
#pragma unroll
  for (int it = 0; it < 2; ++it) {
    int idx = (it * TPB + tid) * 8;
    int dd = idx >> 6, kvo = idx & 63;
    ushort tmp[8];
#pragma unroll
    for (int j = 0; j < 8; ++j) tmp[j] = t[kvo + j][dd];
    *(s16x8*)(vt + ((long)bh * 64 + dd) * 1024 + kv0 + kvo) = *(const s16x8*)tmp;
  }
}

// weight prep ---------------------------------------------------------------
__global__ __launch_bounds__(TPB)
void wt_build(const float* __restrict__ in, ushort* __restrict__ out)
{
  __shared__ float t[64][65];
  const int tid = threadIdx.x;
  const int k0 = blockIdx.x * 64, n0 = blockIdx.y * 64;
#pragma unroll
  for (int it = 0; it < 4; ++it) {
    int idx = it * TPB + tid;
    int r = idx >> 4, c4 = (idx & 15) * 4;
    f32x4 v = *(const f32x4*)&in[(long)(k0 + r) * 1024 + n0 + c4];
    t[r][c4] = v[0]; t[r][c4 + 1] = v[1]; t[r][c4 + 2] = v[2]; t[r][c4 + 3] = v[3];
  }
  __syncthreads();
#pragma unroll
  for (int it = 0; it < 4; ++it) {
    int idx = it * TPB + tid;
    int nr = idx >> 4, k4 = (idx & 15) * 4;
    ushort4 o = { f2bf(t[k4][nr]), f2bf(t[k4 + 1][nr]),
                  f2bf(t[k4 + 2][nr]), f2bf(t[k4 + 3][nr]) };
    *(ushort4*)&out[(long)(n0 + nr) * 1024 + k0 + k4] = o;
  }
}
// per-oi: read w[oi*f .. +f) contiguously, scatter to f tap matrices (coalesced)
__global__ __launch_bounds__(TPB)
void tap_build(const float* __restrict__ w, ushort* __restrict__ out, int f)
{
  long oi = (long)blockIdx.x * TPB + threadIdx.x;
  for (int t = 0; t < f; ++t)
    out[(long)t * 1048576 + oi] = f2bf(w[oi * f + t]);
}
__global__ __launch_bounds__(TPB)
void bn_prep(const float* __restrict__ cb, const float* __restrict__ g,
             const float* __restrict__ bb, const float* __restrict__ m,
             const float* __restrict__ v, float* __restrict__ sc, float* __restrict__ sh)
{
  int i = blockIdx.x * TPB + threadIdx.x;
  float s = g[i] * rsqrtf(v[i] + 1e-5f);
  sc[i] = s;
  sh[i] = (cb[i] - m[i]) * s + bb[i];
}
__global__ __launch_bounds__(TPB)
void qkvb_build(const float* __restrict__ bq, const float* __restrict__ bk,
                const float* __restrict__ bv, float* __restrict__ out)
{
  int i = blockIdx.x * TPB + threadIdx.x;
  out[i] = (i < 1024) ? bq[i] : (i < 2048 ? bk[i - 1024] : bv[i - 2048]);
}
__global__ void zero_ws(ushort* z) { z[threadIdx.x] = 0; }

// ---------------------------------------------------------------------------
extern "C" void kernel_launch(void* const* d_in, const int* in_sizes, int n_in,
                              void* d_out, int out_size, void* d_ws, size_t ws_size,
                              hipStream_t stream)
{
  const float* X  = (const float*)d_in[0];
  const float* Wq = (const float*)d_in[1];
  const float* Wk = (const float*)d_in[2];
  const float* Wv = (const float*)d_in[3];
  const float* Wo = (const float*)d_in[4];
  const float* Bq = (const float*)d_in[5];
  const float* Bk = (const float*)d_in[6];
  const float* Bv = (const float*)d_in[7];
  const float* Bo = (const float*)d_in[8];
  const float *CW[3], *CB[3], *BG[3], *BBe[3], *BMu[3], *BVa[3];
  for (int i = 0; i < 3; ++i) {
    CW[i]  = (const float*)d_in[9 + 6 * i];
    CB[i]  = (const float*)d_in[10 + 6 * i];
    BG[i]  = (const float*)d_in[11 + 6 * i];
    BBe[i] = (const float*)d_in[12 + 6 * i];
    BMu[i] = (const float*)d_in[13 + 6 * i];
    BVa[i] = (const float*)d_in[14 + 6 * i];
  }
  const float* L1a = (const float*)d_in[27];
  const float* L2a = (const float*)d_in[28];
  const float* LFa = (const float*)d_in[29];
  const float* L1b = (const float*)d_in[30];
  const float* L2b = (const float*)d_in[31];
  const float* LFb = (const float*)d_in[32];

  char* p = (char*)d_ws;
  auto carve = [&](size_t bytes) { char* r = p; p += (bytes + 255) & ~(size_t)255; return r; };
  ushort* abuf  = (ushort*)carve(16777216);   // LN out bf16 [8192][1024]
  ushort* wqkvt = (ushort*)carve(6291456);
  ushort* wot   = (ushort*)carve(2097152);
  ushort* wtap  = (ushort*)carve(18874368);   // 9 taps [1024,1024] bf16
  ushort* qkv   = (ushort*)carve(50331648);   // bf16 [8192][3072]
  ushort* vt    = (ushort*)carve(16777216);   // V^T bf16 [128][64][1024]
  ushort* obuf  = (ushort*)carve(16777216);   // attn out bf16 [8192][1024]
  float*  qkvb  = (float*) carve(12288);
  float*  bnsc  = (float*) carve(12288);
  float*  bnsh  = (float*) carve(12288);
  ushort* zp    = (ushort*)carve(256);
  if ((size_t)(p - (char*)d_ws) > ws_size) return;  // ~123 MB; known to fit

  float* xbuf = (float*)d_out;                // residual stream lives in d_out

  // per-call weight prep (graph-safe: identical work every call)
  wt_build<<<dim3(16, 16), TPB, 0, stream>>>(Wq, wqkvt);
  wt_build<<<dim3(16, 16), TPB, 0, stream>>>(Wk, wqkvt + 1048576);
  wt_build<<<dim3(16, 16), TPB, 0, stream>>>(Wv, wqkvt + 2097152);
  wt_build<<<dim3(16, 16), TPB, 0, stream>>>(Wo, wot);
  tap_build<<<4096, TPB, 0, stream>>>(CW[0], wtap, 1);
  tap_build<<<4096, TPB, 0, stream>>>(CW[1], wtap + 1048576, 3);
  tap_build<<<4096, TPB, 0, stream>>>(CW[2], wtap + 4 * 1048576, 5);
  for (int i = 0; i < 3; ++i)
    bn_prep<<<4, TPB, 0, stream>>>(CB[i], BG[i], BBe[i], BMu[i], BVa[i],
                                   bnsc + i * 1024, bnsh + i * 1024);
  qkvb_build<<<12, TPB, 0, stream>>>(Bq, Bk, Bv, qkvb);
  zero_ws<<<1, 128, 0, stream>>>(zp);

  for (int L = 0; L < 2; ++L) {
    const float* xs = (L == 0) ? X : xbuf;
    // ---- x + MHA(LN1(x)) ----
    ln_rows<true><<<8192, TPB, 0, stream>>>(xs, L1a, L1b, abuf);
    gemm_bt2<true, true, false><<<dim3(32, 24), 512, 147456, stream>>>(
        abuf, 1024, wqkvt, 1024, qkv, 3072, qkvb, nullptr, 1024);
    vt_build<<<dim3(16, 128), TPB, 0, stream>>>(qkv, vt);
    flash_attn<<<dim3(8, 128), TPB, 0, stream>>>(qkv, vt, obuf);
    gemm_bt2<false, true, true><<<dim3(32, 8), 512, 147456, stream>>>(
        obuf, 1024, wot, 1024, xbuf, 1024, Bo, xs, 1024);
    // ---- x + FFN(LN2(x)): one fused deep-pipelined dispatch ----
    ln_rows<true><<<8192, TPB, 0, stream>>>(xbuf, L2a, L2b, abuf);
    conv_fused2<<<dim3(32, 8), 512, 147456, stream>>>(abuf, wtap, xbuf, bnsc, bnsh, zp);
  }
  ln_rows<false><<<8192, TPB, 0, stream>>>(xbuf, LFa, LFb, d_out);
}